// Round 1
// baseline (1142.034 us; speedup 1.0000x reference)
//
#include <hip/hip_runtime.h>

// Problem constants (from reference): B=64, TOPK=2, E=16, C=1024, K=4096
#define BB    64
#define TOPK  2
#define EE    16
#define CC    1024
#define KK    4096

constexpr int RPB = 16;        // weight rows (output channels) per block
constexpr int P   = 16;        // pairs (token,slot) processed per group
constexpr int KC  = 512;       // K-chunk staged in LDS
constexpr int KC4 = KC / 4;    // float4s per chunk row (=128)

// ---------------------------------------------------------------------------
// Kernel 1: block 0 builds per-expert routing lists; other blocks initialize
//   out[b,c] = residual[b,c] + sum_s ew[b,s] * bias[idx[b,s], c]
// ---------------------------------------------------------------------------
__global__ __launch_bounds__(256) void route_init(
    const int* __restrict__ idx, const float* __restrict__ ew,
    const float* __restrict__ bias, const float* __restrict__ resid,
    float* __restrict__ out, int* __restrict__ cnt, int* __restrict__ lists)
{
    if (blockIdx.x == 0) {
        __shared__ int scnt[EE];
        if (threadIdx.x < EE) scnt[threadIdx.x] = 0;
        __syncthreads();
        if (threadIdx.x < BB * TOPK) {
            int e = idx[threadIdx.x];
            int pos = atomicAdd(&scnt[e], 1);
            lists[e * 128 + pos] = threadIdx.x;   // pair id = b*TOPK + slot
        }
        __syncthreads();
        if (threadIdx.x < EE) cnt[threadIdx.x] = scnt[threadIdx.x];
    } else {
        int i = (blockIdx.x - 1) * 256 + threadIdx.x;   // i in [0, B*C)
        int b = i >> 10;                                 // C = 1024
        int c = i & (CC - 1);
        float v = resid[i];
#pragma unroll
        for (int s = 0; s < TOPK; s++) {
            int e = idx[b * TOPK + s];
            v += ew[b * TOPK + s] * bias[e * CC + c];
        }
        out[i] = v;
    }
}

// ---------------------------------------------------------------------------
// Kernel 2: grid = E * (C/RPB) blocks. Block (e, ct) streams 16 weight rows
// of expert e exactly once (per pair-group), multiplying against up to P
// activations staged in LDS. Wave w handles rows c0+4w..c0+4w+3.
// ---------------------------------------------------------------------------
__global__ __launch_bounds__(256, 4) void moe_mlp2(
    const float* __restrict__ act, const float* __restrict__ ew,
    const float* __restrict__ W, float* __restrict__ out,
    const int* __restrict__ cnt, const int* __restrict__ lists)
{
    __shared__ float sact[P][KC];   // 32 KB
    __shared__ int   spair[P];

    const int e = blockIdx.x >> 6;            // 64 c-tiles per expert
    const int n = cnt[e];
    if (n == 0) return;                        // unused expert: skip entirely
    const int c0   = (blockIdx.x & 63) * RPB;
    const int tid  = threadIdx.x;
    const int lane = tid & 63;
    const int wave = tid >> 6;
    const float* We = W + (size_t)(e * CC + c0 + wave * 4) * KK;

    for (int g = 0; g < n; g += P) {
        const int np = min(P, n - g);
        if (tid < np) spair[tid] = lists[e * 128 + g + tid];
        __syncthreads();   // spair visible; prev group's LDS readers done

        float acc[4][P];
#pragma unroll
        for (int r = 0; r < 4; r++)
#pragma unroll
            for (int p = 0; p < P; p++) acc[r][p] = 0.f;

        for (int kc = 0; kc < KK; kc += KC) {
            if (kc) __syncthreads();   // prev chunk's compute done before overwrite
            // cooperative stage: np rows x KC floats, float4 per thread
            for (int t = tid; t < np * KC4; t += 256) {
                int p  = t >> 7;                  // KC4 == 128
                int kk = (t & (KC4 - 1)) << 2;
                *(float4*)&sact[p][kk] =
                    *(const float4*)(act + (size_t)spair[p] * KK + kc + kk);
            }
            __syncthreads();
#pragma unroll
            for (int ii = 0; ii < KC4 / 64; ii++) {
                int i = lane + ii * 64;
                float4 w4[4];
#pragma unroll
                for (int r = 0; r < 4; r++)
                    w4[r] = *(const float4*)(We + (size_t)r * KK + kc + 4 * i);
#pragma unroll
                for (int p = 0; p < P; p++) {
                    float4 a4 = *(const float4*)&sact[p][4 * i];
#pragma unroll
                    for (int r = 0; r < 4; r++)
                        acc[r][p] += w4[r].x * a4.x + w4[r].y * a4.y +
                                     w4[r].z * a4.z + w4[r].w * a4.w;
                }
            }
        }

        // wave-wide reduction (64 lanes) then one atomic per (row, pair)
#pragma unroll
        for (int r = 0; r < 4; r++) {
#pragma unroll
            for (int p = 0; p < P; p++) {
                if (p < np) {   // compile-time p => static acc indexing
                    float v = acc[r][p];
#pragma unroll
                    for (int off = 32; off > 0; off >>= 1)
                        v += __shfl_down(v, off, 64);
                    if (lane == 0) {
                        int pr = spair[p];
                        atomicAdd(out + (pr >> 1) * CC + c0 + wave * 4 + r,
                                  ew[pr] * v);
                    }
                }
            }
        }
        __syncthreads();   // all reduction reads of spair/acc done before next group
    }
}

extern "C" void kernel_launch(void* const* d_in, const int* in_sizes, int n_in,
                              void* d_out, int out_size, void* d_ws, size_t ws_size,
                              hipStream_t stream) {
    const float* act   = (const float*)d_in[0];   // [B, TOPK, K]
    const int*   idx   = (const int*)d_in[1];     // [B, TOPK]
    const float* ew    = (const float*)d_in[2];   // [B, TOPK]
    const float* W     = (const float*)d_in[3];   // [E, C, K]
    const float* bias  = (const float*)d_in[4];   // [E, C]
    const float* resid = (const float*)d_in[5];   // [B, C]
    float* out = (float*)d_out;

    int* cnt   = (int*)d_ws;          // 16 ints
    int* lists = (int*)d_ws + 64;     // 16 * 128 ints, 256B-aligned offset

    route_init<<<1 + (BB * CC) / 256, 256, 0, stream>>>(
        idx, ew, bias, resid, out, cnt, lists);
    moe_mlp2<<<EE * (CC / RPB), 256, 0, stream>>>(
        act, ew, W, out, cnt, lists);
}

// Round 2
// 433.090 us; speedup vs baseline: 2.6369x; 2.6369x over previous
//
#include <hip/hip_runtime.h>

// Problem constants (from reference): B=64, TOPK=2, E=16, C=1024, K=4096
#define BB    64
#define TOPK  2
#define EE    16
#define CC    1024
#define KK    4096

constexpr int RPB = 8;         // weight rows (output channels) per block (2/wave)
constexpr int P   = 16;        // pairs (token,slot) processed per group
constexpr int KC  = 512;       // K-chunk staged in LDS
constexpr int KC4 = KC / 4;    // float4s per chunk row (=128)

// ---------------------------------------------------------------------------
// Kernel 1: block 0 builds per-expert routing lists; other blocks initialize
//   out[b,c] = residual[b,c] + sum_s ew[b,s] * bias[idx[b,s], c]
// ---------------------------------------------------------------------------
__global__ __launch_bounds__(256) void route_init(
    const int* __restrict__ idx, const float* __restrict__ ew,
    const float* __restrict__ bias, const float* __restrict__ resid,
    float* __restrict__ out, int* __restrict__ cnt, int* __restrict__ lists)
{
    if (blockIdx.x == 0) {
        __shared__ int scnt[EE];
        if (threadIdx.x < EE) scnt[threadIdx.x] = 0;
        __syncthreads();
        if (threadIdx.x < BB * TOPK) {
            int e = idx[threadIdx.x];
            int pos = atomicAdd(&scnt[e], 1);
            lists[e * 128 + pos] = threadIdx.x;   // pair id = b*TOPK + slot
        }
        __syncthreads();
        if (threadIdx.x < EE) cnt[threadIdx.x] = scnt[threadIdx.x];
    } else {
        int i = (blockIdx.x - 1) * 256 + threadIdx.x;   // i in [0, B*C)
        int b = i >> 10;                                 // C = 1024
        int c = i & (CC - 1);
        float v = resid[i];
#pragma unroll
        for (int s = 0; s < TOPK; s++) {
            int e = idx[b * TOPK + s];
            v += ew[b * TOPK + s] * bias[e * CC + c];
        }
        out[i] = v;
    }
}

// ---------------------------------------------------------------------------
// Kernel 2: grid = E * (C/RPB) blocks. Block (e, ct) streams 8 weight rows
// of expert e exactly once (per pair-group), multiplying against up to P
// activations staged in LDS. Wave w handles rows c0 + 2w, c0 + 2w + 1.
// acc[2][16] = 32 VGPRs/lane — fits without spilling (round-1 failure mode:
// acc[4][16]=64 + launch_bounds(256,4) => full spill, 1.8 GB scratch writes).
// ---------------------------------------------------------------------------
__global__ __launch_bounds__(256, 2) void moe_mlp2(
    const float* __restrict__ act, const float* __restrict__ ew,
    const float* __restrict__ W, float* __restrict__ out,
    const int* __restrict__ cnt, const int* __restrict__ lists)
{
    __shared__ float sact[P][KC];   // 32 KB
    __shared__ int   spair[P];

    const int e = blockIdx.x >> 7;            // 128 c-tiles per expert
    const int n = cnt[e];
    if (n == 0) return;                        // unused expert: skip entirely
    const int c0   = (blockIdx.x & 127) * RPB;
    const int tid  = threadIdx.x;
    const int lane = tid & 63;
    const int wave = tid >> 6;
    const float* We = W + (size_t)(e * CC + c0 + wave * 2) * KK;

    for (int g = 0; g < n; g += P) {
        const int np = min(P, n - g);
        if (tid < np) spair[tid] = lists[e * 128 + g + tid];
        __syncthreads();   // spair visible; prev group's LDS readers done

        float acc[2][P];
#pragma unroll
        for (int r = 0; r < 2; r++)
#pragma unroll
            for (int p = 0; p < P; p++) acc[r][p] = 0.f;

        for (int kc = 0; kc < KK; kc += KC) {
            if (kc) __syncthreads();   // prev chunk's compute done before overwrite
            // cooperative stage: np rows x KC floats, float4 per thread
            for (int t = tid; t < np * KC4; t += 256) {
                int p  = t >> 7;                  // KC4 == 128
                int kk = (t & (KC4 - 1)) << 2;
                *(float4*)&sact[p][kk] =
                    *(const float4*)(act + (size_t)spair[p] * KK + kc + kk);
            }
            __syncthreads();
#pragma unroll
            for (int ii = 0; ii < KC4 / 64; ii++) {
                int i = lane + ii * 64;
                float4 w4[2];
#pragma unroll
                for (int r = 0; r < 2; r++)
                    w4[r] = *(const float4*)(We + (size_t)r * KK + kc + 4 * i);
#pragma unroll
                for (int p = 0; p < P; p++) {
                    float4 a4 = *(const float4*)&sact[p][4 * i];
#pragma unroll
                    for (int r = 0; r < 2; r++)
                        acc[r][p] += w4[r].x * a4.x + w4[r].y * a4.y +
                                     w4[r].z * a4.z + w4[r].w * a4.w;
                }
            }
        }

        // wave-wide reduction (64 lanes) then one atomic per (row, pair)
#pragma unroll
        for (int r = 0; r < 2; r++) {
#pragma unroll
            for (int p = 0; p < P; p++) {
                if (p < np) {   // compile-time p => static acc indexing
                    float v = acc[r][p];
#pragma unroll
                    for (int off = 32; off > 0; off >>= 1)
                        v += __shfl_down(v, off, 64);
                    if (lane == 0) {
                        int pr = spair[p];
                        atomicAdd(out + (pr >> 1) * CC + c0 + wave * 2 + r,
                                  ew[pr] * v);
                    }
                }
            }
        }
        __syncthreads();   // all reduction reads of spair done before next group
    }
}

extern "C" void kernel_launch(void* const* d_in, const int* in_sizes, int n_in,
                              void* d_out, int out_size, void* d_ws, size_t ws_size,
                              hipStream_t stream) {
    const float* act   = (const float*)d_in[0];   // [B, TOPK, K]
    const int*   idx   = (const int*)d_in[1];     // [B, TOPK]
    const float* ew    = (const float*)d_in[2];   // [B, TOPK]
    const float* W     = (const float*)d_in[3];   // [E, C, K]
    const float* bias  = (const float*)d_in[4];   // [E, C]
    const float* resid = (const float*)d_in[5];   // [B, C]
    float* out = (float*)d_out;

    int* cnt   = (int*)d_ws;          // 16 ints
    int* lists = (int*)d_ws + 64;     // 16 * 128 ints, 256B-aligned offset

    route_init<<<1 + (BB * CC) / 256, 256, 0, stream>>>(
        idx, ew, bias, resid, out, cnt, lists);
    moe_mlp2<<<EE * (CC / RPB), 256, 0, stream>>>(
        act, ew, W, out, cnt, lists);
}

// Round 3
// 404.566 us; speedup vs baseline: 2.8229x; 1.0705x over previous
//
#include <hip/hip_runtime.h>

// Problem constants (from reference): B=64, TOPK=2, E=16, C=1024, K=4096
#define BB    64
#define TOPK  2
#define EE    16
#define CC    1024
#define KK    4096

constexpr int RPB = 8;         // weight rows (output channels) per block (2/wave)
constexpr int P   = 16;        // max pairs (token,slot) per group
constexpr int NW  = KK / 4 / 64;   // float4 "windows" per row per lane (=16)

// ---------------------------------------------------------------------------
// Kernel 1: block 0 builds per-expert routing lists; other blocks initialize
//   out[b,c] = residual[b,c] + sum_s ew[b,s] * bias[idx[b,s], c]
// ---------------------------------------------------------------------------
__global__ __launch_bounds__(256) void route_init(
    const int* __restrict__ idx, const float* __restrict__ ew,
    const float* __restrict__ bias, const float* __restrict__ resid,
    float* __restrict__ out, int* __restrict__ cnt, int* __restrict__ lists)
{
    if (blockIdx.x == 0) {
        __shared__ int scnt[EE];
        if (threadIdx.x < EE) scnt[threadIdx.x] = 0;
        __syncthreads();
        if (threadIdx.x < BB * TOPK) {
            int e = idx[threadIdx.x];
            int pos = atomicAdd(&scnt[e], 1);
            lists[e * 128 + pos] = threadIdx.x;   // pair id = b*TOPK + slot
        }
        __syncthreads();
        if (threadIdx.x < EE) cnt[threadIdx.x] = scnt[threadIdx.x];
    } else {
        int i = (blockIdx.x - 1) * 256 + threadIdx.x;   // i in [0, B*C)
        int b = i >> 10;                                 // C = 1024
        int c = i & (CC - 1);
        float v = resid[i];
#pragma unroll
        for (int s = 0; s < TOPK; s++) {
            int e = idx[b * TOPK + s];
            v += ew[b * TOPK + s] * bias[e * CC + c];
        }
        out[i] = v;
    }
}

// ---------------------------------------------------------------------------
// Kernel 2: grid = E * (C/RPB) = 2048 blocks, 256 threads. Block (e, ct)
// streams 8 weight rows of expert e exactly once per pair-group. Wave w owns
// rows c0+2w, c0+2w+1. Activations (2 MB total, L2-resident) are read
// directly from global per lane — NO LDS, NO barriers in the hot loop
// (round-2 lesson: barrier-sandwich K-loop left both pipes <25% busy).
// Pair-chunk guards (wave-uniform) avoid padded FLOPs when np < 16.
// ---------------------------------------------------------------------------
__global__ __launch_bounds__(256) void moe_mlp2(
    const float* __restrict__ act, const float* __restrict__ ew,
    const float* __restrict__ W, float* __restrict__ out,
    const int* __restrict__ cnt, const int* __restrict__ lists)
{
    const int e = blockIdx.x >> 7;            // 128 c-tiles per expert
    const int n = cnt[e];
    if (n == 0) return;                        // unused expert: skip entirely
    const int c0   = (blockIdx.x & 127) * RPB;
    const int lane = threadIdx.x & 63;
    const int wave = threadIdx.x >> 6;
    const float4* We0 = (const float4*)(W + (size_t)(e * CC + c0 + wave * 2) * KK);
    const float4* We1 = We0 + (KK / 4);

    for (int g = 0; g < n; g += P) {
        const int np = min(P, n - g);

        // per-pair act byte offsets — wave-uniform (scalar) loads
        int aoff[P];
#pragma unroll
        for (int p = 0; p < P; p++)
            aoff[p] = (p < np) ? lists[e * 128 + g + p] * (KK * 4) : 0;

        float acc[2][P];
#pragma unroll
        for (int r = 0; r < 2; r++)
#pragma unroll
            for (int p = 0; p < P; p++) acc[r][p] = 0.f;

#pragma unroll 2
        for (int kw = 0; kw < NW; kw++) {
            const int fi = kw * 64 + lane;                 // float4 index in row
            const float4 w0 = We0[fi];
            const float4 w1 = We1[fi];
            const char* abase = (const char*)act + ((size_t)fi << 4);
#pragma unroll
            for (int pc = 0; pc < P / 4; pc++) {
                if (pc * 4 < np) {                          // wave-uniform guard
#pragma unroll
                    for (int j = 0; j < 4; j++) {
                        const int p = pc * 4 + j;
                        const float4 a = *(const float4*)(abase + aoff[p]);
                        acc[0][p] += w0.x * a.x + w0.y * a.y + w0.z * a.z + w0.w * a.w;
                        acc[1][p] += w1.x * a.x + w1.y * a.y + w1.z * a.z + w1.w * a.w;
                    }
                }
            }
        }

        // wave-wide reduction (64 lanes) then one atomic per (row, pair)
#pragma unroll
        for (int p = 0; p < P; p++) {
            if (p < np) {   // compile-time p => static acc indexing
                float v0 = acc[0][p];
                float v1 = acc[1][p];
#pragma unroll
                for (int off = 32; off > 0; off >>= 1) {
                    v0 += __shfl_down(v0, off, 64);
                    v1 += __shfl_down(v1, off, 64);
                }
                if (lane == 0) {
                    int pr = lists[e * 128 + g + p];
                    float w = ew[pr];
                    float* o = out + (pr >> 1) * CC + c0 + wave * 2;
                    atomicAdd(o + 0, w * v0);
                    atomicAdd(o + 1, w * v1);
                }
            }
        }
    }
}

extern "C" void kernel_launch(void* const* d_in, const int* in_sizes, int n_in,
                              void* d_out, int out_size, void* d_ws, size_t ws_size,
                              hipStream_t stream) {
    const float* act   = (const float*)d_in[0];   // [B, TOPK, K]
    const int*   idx   = (const int*)d_in[1];     // [B, TOPK]
    const float* ew    = (const float*)d_in[2];   // [B, TOPK]
    const float* W     = (const float*)d_in[3];   // [E, C, K]
    const float* bias  = (const float*)d_in[4];   // [E, C]
    const float* resid = (const float*)d_in[5];   // [B, C]
    float* out = (float*)d_out;

    int* cnt   = (int*)d_ws;          // 16 ints
    int* lists = (int*)d_ws + 64;     // 16 * 128 ints, 256B-aligned offset

    route_init<<<1 + (BB * CC) / 256, 256, 0, stream>>>(
        idx, ew, bias, resid, out, cnt, lists);
    moe_mlp2<<<EE * (CC / RPB), 256, 0, stream>>>(
        act, ew, W, out, cnt, lists);
}

// Round 4
// 397.386 us; speedup vs baseline: 2.8739x; 1.0181x over previous
//
#include <hip/hip_runtime.h>

// Problem constants (from reference): B=64, TOPK=2, E=16, C=1024, K=4096
#define BB    64
#define TOPK  2
#define EE    16
#define CC    1024
#define KK    4096

constexpr int RPB = 16;            // weight rows per block (4 per wave)
constexpr int P   = 16;            // max pairs (token,slot) per group
constexpr int KS  = 2;             // K-split (partial sums via atomics)
constexpr int KH  = KK / KS;       // floats per K-slice (=2048)
constexpr int NW  = KH / 4 / 64;   // float4 windows per slice per lane (=8)

typedef float v4f __attribute__((ext_vector_type(4)));   // native vec for nt loads

// ---------------------------------------------------------------------------
// Kernel 1: block 0 builds per-expert routing lists; other blocks initialize
//   out[b,c] = residual[b,c] + sum_s ew[b,s] * bias[idx[b,s], c]
// ---------------------------------------------------------------------------
__global__ __launch_bounds__(256) void route_init(
    const int* __restrict__ idx, const float* __restrict__ ew,
    const float* __restrict__ bias, const float* __restrict__ resid,
    float* __restrict__ out, int* __restrict__ cnt, int* __restrict__ lists)
{
    if (blockIdx.x == 0) {
        __shared__ int scnt[EE];
        if (threadIdx.x < EE) scnt[threadIdx.x] = 0;
        __syncthreads();
        if (threadIdx.x < BB * TOPK) {
            int e = idx[threadIdx.x];
            int pos = atomicAdd(&scnt[e], 1);
            lists[e * 128 + pos] = threadIdx.x;   // pair id = b*TOPK + slot
        }
        __syncthreads();
        if (threadIdx.x < EE) cnt[threadIdx.x] = scnt[threadIdx.x];
    } else {
        int i = (blockIdx.x - 1) * 256 + threadIdx.x;   // i in [0, B*C)
        int b = i >> 10;                                 // C = 1024
        int c = i & (CC - 1);
        float v = resid[i];
#pragma unroll
        for (int s = 0; s < TOPK; s++) {
            int e = idx[b * TOPK + s];
            v += ew[b * TOPK + s] * bias[e * CC + c];
        }
        out[i] = v;
    }
}

// ---------------------------------------------------------------------------
// Kernel 2: grid = E * (C/RPB) * KS = 2048 blocks, 256 threads, no LDS, no
// barriers. Block (e, ct, ks) streams RPB=16 weight rows' K-slice of expert e
// exactly once per pair-group (nontemporal: single-use data, keep L2 for act).
// Wave w owns 4 rows; 4 rows/wave halves act re-read traffic vs round 3
// (each act float4 now feeds 16 FMAs). acc[4][16]=64 VGPRs — no min-waves
// launch bound so the allocator has the full 256-VGPR budget (round-1 lesson).
// ---------------------------------------------------------------------------
__global__ __launch_bounds__(256) void moe_mlp2(
    const float* __restrict__ act, const float* __restrict__ ew,
    const float* __restrict__ W, float* __restrict__ out,
    const int* __restrict__ cnt, const int* __restrict__ lists)
{
    const int bid = blockIdx.x;
    const int e = bid >> 7;                   // 128 blocks per expert
    const int n = cnt[e];
    if (n == 0) return;                        // unused expert: skip entirely
    const int ct = (bid >> 1) & 63;
    const int ks = bid & 1;
    const int c0   = ct * RPB;
    const int lane = threadIdx.x & 63;
    const int wave = threadIdx.x >> 6;
    const int row0 = c0 + wave * 4;
    const v4f* __restrict__ Wb =
        (const v4f*)(W + (size_t)(e * CC + row0) * KK + ks * KH);
    const char* __restrict__ actb = (const char*)(act + ks * KH);

    for (int g = 0; g < n; g += P) {
        const int np = min(P, n - g);

        int aoff[P];    // per-pair act byte offsets (wave-uniform values)
        int pid[P];
#pragma unroll
        for (int p = 0; p < P; p++) {
            pid[p]  = (p < np) ? lists[e * 128 + g + p] : 0;
            aoff[p] = pid[p] * (KK * 4);
        }

        float acc[4][P];
#pragma unroll
        for (int r = 0; r < 4; r++)
#pragma unroll
            for (int p = 0; p < P; p++) acc[r][p] = 0.f;

#pragma unroll 2
        for (int kw = 0; kw < NW; kw++) {
            const int fi = kw * 64 + lane;           // float4 idx within slice
            v4f w4[4];
#pragma unroll
            for (int r = 0; r < 4; r++)
                w4[r] = __builtin_nontemporal_load(Wb + (size_t)r * (KK / 4) + fi);
            const char* abase = actb + ((size_t)fi << 4);
#pragma unroll
            for (int pc = 0; pc < P / 4; pc++) {
                if (pc * 4 < np) {                    // wave-uniform guard
#pragma unroll
                    for (int j = 0; j < 4; j++) {
                        const int p = pc * 4 + j;
                        const v4f a = *(const v4f*)(abase + aoff[p]);
#pragma unroll
                        for (int r = 0; r < 4; r++)
                            acc[r][p] += w4[r].x * a.x + w4[r].y * a.y +
                                         w4[r].z * a.z + w4[r].w * a.w;
                    }
                }
            }
        }

        // wave-wide reduction (64 lanes) then one atomic per (row, pair)
#pragma unroll
        for (int p = 0; p < P; p++) {
            if (p < np) {   // compile-time p => static acc indexing
                float v0 = acc[0][p], v1 = acc[1][p];
                float v2 = acc[2][p], v3 = acc[3][p];
#pragma unroll
                for (int off = 32; off > 0; off >>= 1) {
                    v0 += __shfl_down(v0, off, 64);
                    v1 += __shfl_down(v1, off, 64);
                    v2 += __shfl_down(v2, off, 64);
                    v3 += __shfl_down(v3, off, 64);
                }
                if (lane == 0) {
                    int pr = pid[p];
                    float w = ew[pr];
                    float* o = out + (pr >> 1) * CC + row0;
                    atomicAdd(o + 0, w * v0);
                    atomicAdd(o + 1, w * v1);
                    atomicAdd(o + 2, w * v2);
                    atomicAdd(o + 3, w * v3);
                }
            }
        }
    }
}

extern "C" void kernel_launch(void* const* d_in, const int* in_sizes, int n_in,
                              void* d_out, int out_size, void* d_ws, size_t ws_size,
                              hipStream_t stream) {
    const float* act   = (const float*)d_in[0];   // [B, TOPK, K]
    const int*   idx   = (const int*)d_in[1];     // [B, TOPK]
    const float* ew    = (const float*)d_in[2];   // [B, TOPK]
    const float* W     = (const float*)d_in[3];   // [E, C, K]
    const float* bias  = (const float*)d_in[4];   // [E, C]
    const float* resid = (const float*)d_in[5];   // [B, C]
    float* out = (float*)d_out;

    int* cnt   = (int*)d_ws;          // 16 ints
    int* lists = (int*)d_ws + 64;     // 16 * 128 ints, 256B-aligned offset

    route_init<<<1 + (BB * CC) / 256, 256, 0, stream>>>(
        idx, ew, bias, resid, out, cnt, lists);
    moe_mlp2<<<EE * (CC / RPB) * KS, 256, 0, stream>>>(
        act, ew, W, out, cnt, lists);
}

// Round 5
// 394.914 us; speedup vs baseline: 2.8919x; 1.0063x over previous
//
#include <hip/hip_runtime.h>

// Problem constants (from reference): B=64, TOPK=2, E=16, C=1024, K=4096
#define BB    64
#define TOPK  2
#define EE    16
#define CC    1024
#define KK    4096

constexpr int RPB = 16;            // weight rows per block (4 per wave)
constexpr int P   = 16;            // max pairs (token,slot) per group
constexpr int KS  = 4;             // K-split (partial sums via atomics)
constexpr int KH  = KK / KS;       // floats per K-slice (=1024)
constexpr int NW  = KH / 4 / 64;   // float4 windows per slice per lane (=4)

typedef float v4f __attribute__((ext_vector_type(4)));

// ---------------------------------------------------------------------------
// Kernel 1: block 0 builds per-expert routing lists; other blocks initialize
//   out[b,c] = residual[b,c] + sum_s ew[b,s] * bias[idx[b,s], c]
// ---------------------------------------------------------------------------
__global__ __launch_bounds__(256) void route_init(
    const int* __restrict__ idx, const float* __restrict__ ew,
    const float* __restrict__ bias, const float* __restrict__ resid,
    float* __restrict__ out, int* __restrict__ cnt, int* __restrict__ lists)
{
    if (blockIdx.x == 0) {
        __shared__ int scnt[EE];
        if (threadIdx.x < EE) scnt[threadIdx.x] = 0;
        __syncthreads();
        if (threadIdx.x < BB * TOPK) {
            int e = idx[threadIdx.x];
            int pos = atomicAdd(&scnt[e], 1);
            lists[e * 128 + pos] = threadIdx.x;   // pair id = b*TOPK + slot
        }
        __syncthreads();
        if (threadIdx.x < EE) cnt[threadIdx.x] = scnt[threadIdx.x];
    } else {
        int i = (blockIdx.x - 1) * 256 + threadIdx.x;   // i in [0, B*C)
        int b = i >> 10;                                 // C = 1024
        int c = i & (CC - 1);
        float v = resid[i];
#pragma unroll
        for (int s = 0; s < TOPK; s++) {
            int e = idx[b * TOPK + s];
            v += ew[b * TOPK + s] * bias[e * CC + c];
        }
        out[i] = v;
    }
}

// ---------------------------------------------------------------------------
// Kernel 2: grid = E * (C/RPB) * KS = 4096 blocks, 256 threads.
// Round-4 lesson: the fused load/compute loop is latency-bound (too few
// outstanding VMEM loads between waitcnts). New structure:
//   1. Prefetch the ENTIRE per-wave weight slice (4 rows x 1KB = 16 nt
//      dwordx4) into registers in one burst — 16 KB/wave in flight.
//   2. Stage act rows into LDS via global_load_lds (async, no VGPR
//      round-trip), drained by ONE barrier that overlaps the prefetch.
//   3. Hot loop: pure ds_read_b128 + FMA. No global loads, no vmcnt waits.
// Weights stay in registers across pair-groups -> exactly-once weight read.
// ---------------------------------------------------------------------------
__global__ __launch_bounds__(256) void moe_mlp2(
    const float* __restrict__ act, const float* __restrict__ ew,
    const float* __restrict__ W, float* __restrict__ out,
    const int* __restrict__ cnt, const int* __restrict__ lists)
{
    __shared__ float sact[P][KH];   // 16 x 1024 x 4B = 64 KB exactly

    const int bid = blockIdx.x;
    const int e   = bid >> 8;                 // 256 blocks per expert
    const int n   = cnt[e];
    if (n == 0) return;
    const int ct   = (bid >> 2) & 63;
    const int ks   = bid & 3;
    const int lane = threadIdx.x & 63;
    const int wave = threadIdx.x >> 6;
    const int row0 = ct * RPB + wave * 4;

    // --- weight slice prefetch: 16 nt loads, issued back-to-back ---
    const v4f* __restrict__ Wb =
        (const v4f*)(W + (size_t)(e * CC + row0) * KK + ks * KH);
    v4f w[4][NW];
#pragma unroll
    for (int r = 0; r < 4; r++)
#pragma unroll
        for (int kw = 0; kw < NW; kw++)
            w[r][kw] = __builtin_nontemporal_load(
                Wb + (size_t)r * (KK / 4) + kw * 64 + lane);

    for (int g = 0; g < n; g += P) {
        const int np = min(P, n - g);
        if (g) __syncthreads();   // prev group's compute done before re-stage

        // --- async global->LDS staging: wave w stages its quarter of every
        //     row; lds dest = wave-uniform base + lane*16 (HW rule) ---
        for (int p = 0; p < np; p++) {
            int pr = lists[e * 128 + g + p];
            const float* gsrc =
                act + (size_t)pr * KK + ks * KH + (wave * 64 + lane) * 4;
            __builtin_amdgcn_global_load_lds(
                (const __attribute__((address_space(1))) void*)gsrc,
                (__attribute__((address_space(3))) void*)&sact[p][wave * 256],
                16, 0, 0);
        }
        __syncthreads();   // drains lds-loads AND the weight prefetch

        float acc[4][P];
#pragma unroll
        for (int r = 0; r < 4; r++)
#pragma unroll
            for (int p = 0; p < P; p++) acc[r][p] = 0.f;

#pragma unroll
        for (int kw = 0; kw < NW; kw++) {
            const int fb = (kw * 64 + lane) * 4;     // float idx within slice
#pragma unroll
            for (int pc = 0; pc < P / 4; pc++) {
                if (pc * 4 < np) {                    // wave-uniform guard
#pragma unroll
                    for (int j = 0; j < 4; j++) {
                        const int p = pc * 4 + j;
                        const v4f a = *(const v4f*)&sact[p][fb];
#pragma unroll
                        for (int r = 0; r < 4; r++)
                            acc[r][p] += w[r][kw].x * a.x + w[r][kw].y * a.y +
                                         w[r][kw].z * a.z + w[r][kw].w * a.w;
                    }
                }
            }
        }

        // wave-wide reduction (64 lanes) then one atomic per (row, pair)
#pragma unroll
        for (int p = 0; p < P; p++) {
            if (p < np) {   // compile-time p => static acc indexing
                float v0 = acc[0][p], v1 = acc[1][p];
                float v2 = acc[2][p], v3 = acc[3][p];
#pragma unroll
                for (int off = 32; off > 0; off >>= 1) {
                    v0 += __shfl_down(v0, off, 64);
                    v1 += __shfl_down(v1, off, 64);
                    v2 += __shfl_down(v2, off, 64);
                    v3 += __shfl_down(v3, off, 64);
                }
                if (lane == 0) {
                    int pr = lists[e * 128 + g + p];
                    float wgt = ew[pr];
                    float* o = out + (pr >> 1) * CC + row0;
                    atomicAdd(o + 0, wgt * v0);
                    atomicAdd(o + 1, wgt * v1);
                    atomicAdd(o + 2, wgt * v2);
                    atomicAdd(o + 3, wgt * v3);
                }
            }
        }
    }
}

extern "C" void kernel_launch(void* const* d_in, const int* in_sizes, int n_in,
                              void* d_out, int out_size, void* d_ws, size_t ws_size,
                              hipStream_t stream) {
    const float* act   = (const float*)d_in[0];   // [B, TOPK, K]
    const int*   idx   = (const int*)d_in[1];     // [B, TOPK]
    const float* ew    = (const float*)d_in[2];   // [B, TOPK]
    const float* W     = (const float*)d_in[3];   // [E, C, K]
    const float* bias  = (const float*)d_in[4];   // [E, C]
    const float* resid = (const float*)d_in[5];   // [B, C]
    float* out = (float*)d_out;

    int* cnt   = (int*)d_ws;          // 16 ints
    int* lists = (int*)d_ws + 64;     // 16 * 128 ints, 256B-aligned offset

    route_init<<<1 + (BB * CC) / 256, 256, 0, stream>>>(
        idx, ew, bias, resid, out, cnt, lists);
    moe_mlp2<<<EE * (CC / RPB) * KS, 256, 0, stream>>>(
        act, ew, W, out, cnt, lists);
}